// Round 14
// baseline (459.488 us; speedup 1.0000x reference)
//
#include <hip/hip_runtime.h>
#include <hip/hip_bf16.h>
#include <stdint.h>

typedef __attribute__((ext_vector_type(4))) float f32x4;
typedef __attribute__((ext_vector_type(8))) short short8v;

typedef __attribute__((address_space(1))) void gvoid;
typedef __attribute__((address_space(3))) void lvoid;

#define GLD16(gp, lp) __builtin_amdgcn_global_load_lds((const gvoid*)(gp), (lvoid*)(lp), 16, 0, 0)

__device__ __forceinline__ unsigned short f2bf(float f) {
    union { float ff; unsigned uu; } a; a.ff = f;
    unsigned u = a.uu;
    u += 0x7FFFu + ((u >> 16) & 1u);   // RNE; inputs finite
    return (unsigned short)(u >> 16);
}

// ---- fused: Ub[o][r] = bf16(U[o][r]*(S[r]+eps[r]))  (blocks 0..8191)
//             VtT[k][r] = bf16(Vt[r][k])              (blocks 8192..12287)
__global__ __launch_bounds__(256) void prep_fused_kernel(
    const float* __restrict__ U, const float* __restrict__ S,
    const float* __restrict__ eps, unsigned short* __restrict__ Ub,
    const float* __restrict__ Vt, unsigned short* __restrict__ VtT) {
    __shared__ float tile[64][65];
    if (blockIdx.x < 8192) {
        long idx = ((long)blockIdx.x * 256 + threadIdx.x) * 8;
        int r = (int)(idx & 4095);
        f32x4 u0 = *(const f32x4*)(U + idx);
        f32x4 u1 = *(const f32x4*)(U + idx + 4);
        f32x4 s0 = *(const f32x4*)(S + r);
        f32x4 s1 = *(const f32x4*)(S + r + 4);
        f32x4 e0 = *(const f32x4*)(eps + r);
        f32x4 e1 = *(const f32x4*)(eps + r + 4);
        union { uint4 v; unsigned short s[8]; } o;
#pragma unroll
        for (int j = 0; j < 4; ++j) {
            o.s[j]     = f2bf(u0[j] * (s0[j] + e0[j]));
            o.s[j + 4] = f2bf(u1[j] * (s1[j] + e1[j]));
        }
        *(uint4*)(Ub + idx) = o.v;
    } else {
        int t  = blockIdx.x - 8192;
        int k0 = (t & 63) << 6;
        int r0 = (t >> 6) << 6;
        int tx = threadIdx.x & 63;
        int tq = threadIdx.x >> 6;
#pragma unroll
        for (int i = 0; i < 16; ++i) {
            int row = (i << 2) + tq;
            tile[row][tx] = Vt[(long)(r0 + row) * 4096 + k0 + tx];
        }
        __syncthreads();
#pragma unroll
        for (int i = 0; i < 16; ++i) {
            int krow = (i << 2) + tq;
            VtT[(long)(k0 + krow) * 4096 + r0 + tx] = f2bf(tile[tx][krow]);
        }
    }
}

// ---- generic fp32 -> bf16 convert (fallback path only) ----
__global__ __launch_bounds__(256) void cvt_bf16_kernel(
    const float* __restrict__ src, unsigned short* __restrict__ dst) {
    long idx = ((long)blockIdx.x * 256 + threadIdx.x) * 8;
    f32x4 v0 = *(const f32x4*)(src + idx);
    f32x4 v1 = *(const f32x4*)(src + idx + 4);
    union { uint4 v; unsigned short s[8]; } o;
#pragma unroll
    for (int j = 0; j < 4; ++j) {
        o.s[j]     = f2bf(v0[j]);
        o.s[j + 4] = f2bf(v1[j]);
    }
    *(uint4*)(dst + idx) = o.v;
}

// =====================================================================
// 256x256-tile NT GEMM, 16 WAVES (1024 thr, 4 waves/SIMD), 4 phases/
// iter, single barrier per phase, uniform vmcnt(2) ring.
// C[M][N] = A[M][K] * B[N][K]^T (+bias). bf16 in, fp32 acc.
// Wave grid 4M x 4N, wave tile 64x64 (acc 64 VGPR -> total ~115 <=128,
// launch_bounds(1024,4) => 4 waves/SIMD, 16 waves/CU).
//
// Rationale (r6-r13): all schedule levers plateaued at ~54% MfmaUtil
// because 2 waves/SIMD can't cover the per-wave read-wall. This trades
// +33% LDS read traffic (B x4) for 2x SIMD TLP; compiler-counted
// lgkmcnt (plain C++ ds_reads, no walls) + HW wave scheduling do the
// overlap. LDS ring identical to r8-r13: 4 regions (buf,kh) of
// [256 rows][32 k] per matrix, XOR slot^=(row>>1)&3 both-sides
// (0 conflicts measured).
//
// Phase t (t=1..4): { read region r(t-1) frags (A4+B4 per wave);
//   [P1: cvt weave]; stage region r(t+2 mod 4) A+B (1 GLD16 each);
//   MFMA16; vmcnt(2); s_barrier }.
// RAW: stage@t confirmed by VM(2) at t+1-end (keeps only t+1's 2
// stages), read at t+3 or later. WAR: region read@t drains before own
// MFMA@t (compiler lgkm) -> before t-end barrier; re-stage >=1 barrier
// later. Prologue: stage r0,r1,r2 (6 loads), VM(2) -> r0,r1 landed;
// r2 confirmed at P1-end. Tail: wrapped dead stages keep ring uniform.
// =====================================================================
#define MM(a, b, c) __builtin_amdgcn_mfma_f32_16x16x32_bf16(a, b, c, 0, 0, 0)

#define ARG(r) (As + (r) * 8192)
#define BRG(r) (Bs + (r) * 8192)

#define STAGE_A(r, koff) GLD16(A + gAr + (koff), ARG(r) + wave * 512)
#define STAGE_B(r, koff) GLD16(B + gBr + (koff), BRG(r) + wave * 512)

#define LOAD_A(r) do { \
    const unsigned short* _p = ARG(r) + aBase; \
    _Pragma("unroll") \
    for (int _m = 0; _m < 4; ++_m) aR[_m] = *(const short8v*)(_p + _m * 512); } while (0)

#define READ_B(r) do { \
    const unsigned short* _p = BRG(r) + bBase; \
    _Pragma("unroll") \
    for (int _n = 0; _n < 4; ++_n) bR[_n] = *(const short8v*)(_p + _n * 512); } while (0)

#define MFMA16 do { \
    __builtin_amdgcn_s_setprio(1); \
    _Pragma("unroll") \
    for (int _m = 0; _m < 4; ++_m) { \
        acc[_m][0] = MM(aR[_m], bR[0], acc[_m][0]); \
        acc[_m][1] = MM(aR[_m], bR[1], acc[_m][1]); \
        acc[_m][2] = MM(aR[_m], bR[2], acc[_m][2]); \
        acc[_m][3] = MM(aR[_m], bR[3], acc[_m][3]); \
    } \
    __builtin_amdgcn_s_setprio(0); } while (0)

#define VM2 asm volatile("s_waitcnt vmcnt(2)" ::: "memory")
#define BAR __builtin_amdgcn_s_barrier()

// Standard phase: read region rd, stage region st at k-offset sk.
#define PHASE(rd, st, sk) do { \
    LOAD_A(rd); READ_B(rd); \
    STAGE_A(st, sk); STAGE_B(st, sk); \
    MFMA16; \
    VM2; BAR; } while (0)

template<int OUT_BF16, int BIAS, int DO_CVT>
__global__ __launch_bounds__(1024, 4) void gemm256_kernel(
    const unsigned short* __restrict__ A,   // [M][K] bf16 bits
    const unsigned short* __restrict__ B,   // [N][K] bf16 bits
    void* __restrict__ Cv, const float* __restrict__ bias,
    const float* __restrict__ xsrc, unsigned short* __restrict__ xdst,
    int M, int N, int K) {
    __shared__ unsigned short As[4 * 8192];   // 64 KB
    __shared__ unsigned short Bs[4 * 8192];   // 64 KB

    const int tid  = threadIdx.x;
    const int wave = tid >> 6;
    const int lane = tid & 63;
    const int fr   = lane & 15;
    const int fq   = lane >> 4;

    // XCD-aware bijective swizzle + n-pair clustering (r12, verified)
    const int nwg = gridDim.x;
    const int bid = blockIdx.x;
    const int cpx = nwg >> 3;
    const int wg  = (bid & 7) * cpx + (bid >> 3);
    const int nmt = M >> 8;
    const long n0 = (long)(2 * (wg / cpx) + (wg & 1)) << 8;
    const long m0 = (long)((wg >> 1) & (nmt - 1)) << 8;

    const int wwr = wave >> 2;   // 0..3  (M quarter)
    const int wwc = wave & 3;    // 0..3  (N quarter)

    // Stage addressing (verified r3-r13): region [256 rows][32 k] bf16,
    // 1024 16B slots; slot si = tid; global src slot = (si&3)^((row>>1)&3).
    const int  rS  = tid >> 2;                        // row 0..255
    const int  sS  = (tid & 3) ^ ((rS >> 1) & 3);
    const long gAr = (m0 + rS) * K + sS * 8;
    const long gBr = (n0 + rS) * K + sS * 8;

    // ds_read (swizzled): elem = row*32 + ((fq ^ ((row>>1)&3))*8)
    const int swz   = (fq ^ ((fr >> 1) & 3)) * 8;
    const int aBase = (wwr * 64 + fr) * 32 + swz;
    const int bBase = (wwc * 64 + fr) * 32 + swz;

    f32x4  acc[4][4] = {};
    short8v aR[4], bR[4];

    // cvt weave state (GEMM1 only): 4 f32 per thread per iter.
    f32x4 xv;
    unsigned long long xaddr = 0;
    unsigned short* xs = nullptr;
    if constexpr (DO_CVT) {
        long base = (long)bid * 4096 + (long)tid * 4;
        xaddr = (unsigned long long)(uintptr_t)(xsrc + base);
        xs = xdst + base;
    }

    // Prologue: stage r0@k0, r1@k32, r2@k64 (6 loads); VM2 -> r0,r1 in.
    STAGE_A(0, 0);  STAGE_B(0, 0);
    STAGE_A(1, 32); STAGE_B(1, 32);
    STAGE_A(2, 64); STAGE_B(2, 64);
    VM2;
    BAR;

    const int nIter = K >> 7;   // 4 phases x K=32 per iteration
    for (int i = 0; i < nIter; ++i) {
        const int kA = 128 * i + 96;                    // r3 (in-bounds)
        int k0n = 128 * i + 128; if (k0n >= K) k0n -= K; // wrap: dead
        int k1n = 128 * i + 160; if (k1n >= K) k1n -= K;
        int k2n = 128 * i + 192; if (k2n >= K) k2n -= K;

        if constexpr (DO_CVT) {
            // P1 + cvt weave: store chunk i-1, load chunk i.
            LOAD_A(0); READ_B(0);
            if (i) {
                union { unsigned uu[2]; unsigned short s[4]; } o;
#pragma unroll
                for (int j = 0; j < 4; ++j) o.s[j] = f2bf(xv[j]);
                *(uint2*)xs = *(uint2*)o.uu;
                xs += 1048576;                          // 1M bf16 per iter
            }
            asm volatile("global_load_dwordx4 %0, %1, off"
                         : "=v"(xv) : "v"(xaddr));
            xaddr += 4194304ull;                        // 1M f32 per iter
            STAGE_A(3, kA); STAGE_B(3, kA);
            MFMA16;
            VM2; BAR;
        } else {
            PHASE(0, 3, kA);     // P1: read r0, stage r3@k+96
        }
        PHASE(1, 0, k0n);        // P2: read r1, stage r0'@k+128
        PHASE(2, 1, k1n);        // P3: read r2, stage r1'@k+160
        PHASE(3, 2, k2n);        // P4: read r3, stage r2'@k+192
    }

    if constexpr (DO_CVT) {      // final chunk store (load drained by VM2)
        union { unsigned uu[2]; unsigned short s[4]; } o;
#pragma unroll
        for (int j = 0; j < 4; ++j) o.s[j] = f2bf(xv[j]);
        *(uint2*)xs = *(uint2*)o.uu;
    }

    // Epilogue: C/D layout col = lane&15, row = (lane>>4)*4 + j
#pragma unroll
    for (int nf = 0; nf < 4; ++nf) {
        const int col = (int)n0 + wwc * 64 + nf * 16 + fr;
        float bv = BIAS ? bias[col] : 0.0f;
#pragma unroll
        for (int mf = 0; mf < 4; ++mf) {
            f32x4 v = acc[mf][nf];
            long rowb = m0 + wwr * 64 + mf * 16 + fq * 4;
#pragma unroll
            for (int j = 0; j < 4; ++j) {
                float val = v[j] + bv;
                long off = (rowb + j) * N + col;
                if (OUT_BF16) ((unsigned short*)Cv)[off] = f2bf(val);
                else          ((float*)Cv)[off] = val;
            }
        }
    }
}

extern "C" void kernel_launch(void* const* d_in, const int* in_sizes, int n_in,
                              void* d_out, int out_size, void* d_ws, size_t ws_size,
                              hipStream_t stream) {
    const float* x    = (const float*)d_in[0];   // [4,2048,4096] = [8192][4096]
    const float* U    = (const float*)d_in[1];   // [4096][4096]
    const float* S    = (const float*)d_in[2];   // [4096]
    const float* Vt   = (const float*)d_in[3];   // [4096][4096]
    const float* eps  = (const float*)d_in[4];   // [4096]
    const float* bias = (const float*)d_in[5];   // [4096]
    float* out = (float*)d_out;                  // [8192][4096] fp32

    char* ws = (char*)d_ws;
    unsigned short* Ub  = (unsigned short*)(ws);                       // 32 MB
    unsigned short* VtT = (unsigned short*)(ws + (size_t)(32 << 20));  // 32 MB
    unsigned short* Wb  = (unsigned short*)(ws + (size_t)(64 << 20));  // 32 MB

    // 1) Ub = bf16(U*(S+eps)) ; VtT = bf16(Vt^T)   (fused, independent)
    prep_fused_kernel<<<12288, 256, 0, stream>>>(U, S, eps, Ub, Vt, VtT);

    if (ws_size >= ((size_t)160 << 20)) {
        // Fused path: GEMM1 also streams x -> Xb (at ws+96MB, no alias).
        unsigned short* Xb = (unsigned short*)(ws + ((size_t)96 << 20));
        gemm256_kernel<1, 0, 1><<<256, 1024, 0, stream>>>(
            Ub, VtT, (void*)Wb, nullptr, x, Xb, 4096, 4096, 4096);
        gemm256_kernel<0, 1, 0><<<512, 1024, 0, stream>>>(
            Xb, Wb, (void*)out, bias, nullptr, nullptr, 8192, 4096, 4096);
    } else {
        // Fallback: sequential cvt, Xb over Ub/VtT (dead after GEMM1).
        unsigned short* Xb = (unsigned short*)(ws);
        gemm256_kernel<1, 0, 0><<<256, 1024, 0, stream>>>(
            Ub, VtT, (void*)Wb, nullptr, nullptr, nullptr, 4096, 4096, 4096);
        cvt_bf16_kernel<<<16384, 256, 0, stream>>>(x, Xb);
        gemm256_kernel<0, 1, 0><<<512, 1024, 0, stream>>>(
            Xb, Wb, (void*)out, bias, nullptr, nullptr, 8192, 4096, 4096);
    }
}